// Round 2
// baseline (1734.948 us; speedup 1.0000x reference)
//
#include <hip/hip_runtime.h>
#include <cstdint>

#define HH 72
#define NR 8
#define NTH 256
#define TT 512

#if __has_builtin(__builtin_amdgcn_exp2f)
#define EXP2(x) __builtin_amdgcn_exp2f(x)
#else
#define EXP2(x) exp2f(x)
#endif
#if __has_builtin(__builtin_amdgcn_rcpf)
#define RCP(x) __builtin_amdgcn_rcpf(x)
#else
#define RCP(x) (1.0f/(x))
#endif

__device__ __forceinline__ float fsig(float x) {
  float e = EXP2(x * -1.442695040888963f);
  return RCP(1.0f + e);
}
__device__ __forceinline__ float ftanh(float x) {
  float e = EXP2(x * -2.885390081777927f);
  return fmaf(2.0f, RCP(1.0f + e), -1.0f);
}

// accumulate 8 rows: A[r] += W_ * P_[r], P_ points to 8 contiguous floats (32B aligned)
// NOTE: macro params must not collide with .x/.y/.z/.w member tokens!
#define FMA8(A, W_, P_) { \
  const float4 _fa = *(const float4*)(P_); \
  const float4 _fb = *(const float4*)(((const float*)(P_)) + 4); \
  A[0] = fmaf((W_), _fa.x, A[0]); A[1] = fmaf((W_), _fa.y, A[1]); \
  A[2] = fmaf((W_), _fa.z, A[2]); A[3] = fmaf((W_), _fa.w, A[3]); \
  A[4] = fmaf((W_), _fb.x, A[4]); A[5] = fmaf((W_), _fb.y, A[5]); \
  A[6] = fmaf((W_), _fb.z, A[6]); A[7] = fmaf((W_), _fb.w, A[7]); }

// counting sort of rows by h_lens so blocks get similar-length rows
__global__ void cfm_sort(const int* __restrict__ h_lens, int* __restrict__ perm) {
  __shared__ int hist[257];
  __shared__ int offs[257];
  const int t = threadIdx.x; // 256 threads
  for (int i = t; i < 257; i += NTH) hist[i] = 0;
  __syncthreads();
  for (int i = t; i < 2048; i += NTH) {
    int bkt = min(max(h_lens[i] - 256, 0), 256);
    atomicAdd(&hist[bkt], 1);
  }
  __syncthreads();
  if (t == 0) { int s = 0; for (int i = 0; i < 257; ++i) { offs[i] = s; s += hist[i]; } }
  __syncthreads();
  for (int i = t; i < 2048; i += NTH) {
    int bkt = min(max(h_lens[i] - 256, 0), 256);
    int pos = atomicAdd(&offs[bkt], 1);
    perm[pos] = i;
  }
}

__global__ __launch_bounds__(NTH, 1)
void cfm_main(const float* __restrict__ x, const float* __restrict__ rnn,
              const float* __restrict__ deltas, const int* __restrict__ h_lens,
              const float* __restrict__ W_ih, const float* __restrict__ W_hh,
              const float* __restrict__ b_ih, const float* __restrict__ b_hh,
              const float* __restrict__ eW1, const float* __restrict__ eb1,
              const float* __restrict__ eW2, const float* __restrict__ eb2,
              const float* __restrict__ eW3, const float* __restrict__ eb3,
              const float* __restrict__ dW1, const float* __restrict__ db1,
              const float* __restrict__ dW2, const float* __restrict__ db2,
              const float* __restrict__ dW3, const float* __restrict__ db3,
              const int* __restrict__ perm, float* __restrict__ out)
{
  __shared__ __align__(16) float hS[HH][NR];       // h, [k][r]
  __shared__ __align__(16) float hT[NR][80];       // h transposed, padded
  __shared__ __align__(16) float gS[288*9];        // gates [j][9]; also enc z1S, dec d2S
  __shared__ __align__(16) float rnnS[32*9*NR];    // rnn chunk [tc][k][r]; also enc z2S, dec d1S
  __shared__ __align__(16) float d1T[NR][288];     // dec layer1 transposed
  __shared__ __align__(16) float WxZ[2304];        // extra-gate weights, zipped [k4][j32][4]
  __shared__ __align__(16) float snapP[NR][HH];
  __shared__ __align__(16) float snapC[NR][HH];
  __shared__ __align__(16) float xS[8][NR];
  __shared__ int brS[NR];
  __shared__ int idxS[NR];
  __shared__ float dS[NR];

  const int t  = threadIdx.x;
  const int bb = blockIdx.x;

  if (t < NR) {
    int row = perm ? perm[bb*NR + t] : (bb*NR + t);
    brS[t]  = row;
    idxS[t] = h_lens[row] - 1;   // in [255, 511]
  }
  __syncthreads();

  int maxIdx = idxS[0];
  #pragma unroll
  for (int r = 1; r < NR; ++r) maxIdx = max(maxIdx, idxS[r]);

  const int j2 = 256 + (t & 31);   // extra gate column
  const int er = t >> 5;           // extra gate row

  // elementwise pair ownership: p = r*72 + u, pairs {t, t+256, t+512(t<64)}
  const int pu0 = t % 72,         pr0 = t / 72;
  const int pu1 = (t + 256) % 72, pr1 = (t + 256) / 72;
  const int pu2 = 8 + t,          pr2 = 7;            // valid for t<64
  const int pidx0 = idxS[pr0];
  const int pidx1 = idxS[pr1];
  const int pidx2 = (t < 64) ? idxS[7] : 0;
  float pc0 = 0.f, pc1 = 0.f, pc2 = 0.f;

  // ---------------- encoder: 8 -> 256 -> 256 -> 64 ----------------
  if (t < 64) { int r = t >> 3, k = t & 7; xS[k][r] = x[brS[r]*8 + k]; }
  __syncthreads();

  float* z1S = gS;   // [k][8]
  {
    float acc[NR];
    float b = eb1[t];
    #pragma unroll
    for (int r = 0; r < NR; ++r) acc[r] = b;
    #pragma unroll
    for (int k = 0; k < 8; ++k) { float w = eW1[t*8 + k]; FMA8(acc, w, &xS[k][0]); }
    #pragma unroll
    for (int r = 0; r < NR; ++r) z1S[t*8 + r] = ftanh(acc[r]);
  }
  __syncthreads();
  float* z2S = rnnS; // [k][8]
  {
    float acc[NR];
    float b = eb2[t];
    #pragma unroll
    for (int r = 0; r < NR; ++r) acc[r] = b;
    const float4* w4 = (const float4*)(eW2 + t*256);
    #pragma unroll 4
    for (int k4 = 0; k4 < 64; ++k4) {
      float4 w = w4[k4];
      FMA8(acc, w.x, z1S + (4*k4+0)*8);
      FMA8(acc, w.y, z1S + (4*k4+1)*8);
      FMA8(acc, w.z, z1S + (4*k4+2)*8);
      FMA8(acc, w.w, z1S + (4*k4+3)*8);
    }
    #pragma unroll
    for (int r = 0; r < NR; ++r) z2S[t*8 + r] = ftanh(acc[r]);
  }
  __syncthreads();
  if (t < 64) {                       // h0 (linear) -> hS rows 8..71
    float acc[NR];
    float b = eb3[t];
    #pragma unroll
    for (int r = 0; r < NR; ++r) acc[r] = b;
    const float4* w4 = (const float4*)(eW3 + t*256);
    #pragma unroll 4
    for (int k4 = 0; k4 < 64; ++k4) {
      float4 w = w4[k4];
      FMA8(acc, w.x, z2S + (4*k4+0)*8);
      FMA8(acc, w.y, z2S + (4*k4+1)*8);
      FMA8(acc, w.z, z2S + (4*k4+2)*8);
      FMA8(acc, w.w, z2S + (4*k4+3)*8);
    }
    #pragma unroll
    for (int r = 0; r < NR; ++r) { hS[8+t][r] = acc[r]; hT[r][8+t] = acc[r]; }
  } else if (t < 128) {               // x part -> hS rows 0..7
    int tt2 = t - 64; int r = tt2 >> 3, k = tt2 & 7;
    float v = xS[k][r]; hS[k][r] = v; hT[r][k] = v;
  }

  // LSTM weights: main gate column in registers, extra-gate columns in LDS zip
  float wcol[HH], wih[9], wih2[9];
  #pragma unroll
  for (int k4 = 0; k4 < 18; ++k4) {
    float4 a = *(const float4*)(W_hh + t*HH + 4*k4);
    wcol[4*k4+0] = a.x; wcol[4*k4+1] = a.y; wcol[4*k4+2] = a.z; wcol[4*k4+3] = a.w;
  }
  #pragma unroll
  for (int k = 0; k < 9; ++k) { wih[k] = W_ih[t*9 + k]; wih2[k] = W_ih[j2*9 + k]; }
  const float bias1 = b_ih[t]  + b_hh[t];
  const float bias2 = b_ih[j2] + b_hh[j2];

  auto load_wxz = [&](const float* Wsrc) {
    #pragma unroll
    for (int i = 0; i < 9; ++i) {
      int e = t + NTH*i;            // 0..2303
      int j32 = e / 72, k = e % 72;
      WxZ[(k >> 2)*128 + j32*4 + (k & 3)] = Wsrc[(256 + j32)*HH + k];
    }
  };
  load_wxz(W_hh);
  __syncthreads();

#define PAIR(u, r, c, idxv) { \
    float iv = fsig (gS[(u)*9        + (r)]); \
    float fv = fsig (gS[(72 + (u))*9 + (r)]); \
    float gv = ftanh(gS[(144 + (u))*9 + (r)]); \
    float ov = fsig (gS[(216 + (u))*9 + (r)]); \
    (c) = fmaf(fv, (c), iv*gv); \
    float hv = ov * ftanh(c); \
    hS[(u)][(r)] = hv; hT[(r)][(u)] = hv; \
    if (step == (idxv) - 1) snapP[(r)][(u)] = hv; \
    if (step == (idxv))     snapC[(r)][(u)] = hv; }

  // ---------------- LSTM over time ----------------
  int step = 0;
  for (int chunk = 0; chunk*32 <= maxIdx; ++chunk) {
    // stage 32 steps of rnn_input, transposed to [tc][k][r]
    #pragma unroll
    for (int i = 0; i < 9; ++i) {
      int e = t + NTH*i;            // 0..2303
      int r = e / 288, pos = e % 288;
      rnnS[pos*8 + r] = rnn[brS[r]*4608 + chunk*288 + pos];
    }
    __syncthreads();
    int lim = min(31, maxIdx - chunk*32);
    for (int tt = 0; tt <= lim; ++tt, ++step) {
      float acc[NR];
      #pragma unroll
      for (int r = 0; r < NR; ++r) acc[r] = bias1;
      float acce = bias2;
      const float* rb = rnnS + tt*72;
      #pragma unroll
      for (int k = 0; k < 9; ++k) {
        FMA8(acc, wih[k], rb + k*8);
        acce = fmaf(wih2[k], rb[k*8 + er], acce);
      }
      #pragma unroll
      for (int k = 0; k < HH; ++k) { FMA8(acc, wcol[k], &hS[k][0]); }
      #pragma unroll
      for (int k4 = 0; k4 < 18; ++k4) {
        float4 wz = *(const float4*)&WxZ[(k4*32 + (t & 31))*4];
        float4 hv = *(const float4*)&hT[er][4*k4];
        acce = fmaf(wz.x, hv.x, acce);
        acce = fmaf(wz.y, hv.y, acce);
        acce = fmaf(wz.z, hv.z, acce);
        acce = fmaf(wz.w, hv.w, acce);
      }
      #pragma unroll
      for (int r = 0; r < NR; ++r) gS[t*9 + r] = acc[r];
      gS[j2*9 + er] = acce;
      __syncthreads();
      PAIR(pu0, pr0, pc0, pidx0);
      PAIR(pu1, pr1, pc1, pidx1);
      if (t < 64) PAIR(pu2, pr2, pc2, pidx2);
      __syncthreads();
    }
  }

  // ---------------- decoder: 72 -> 288 -> 288 -> 8 ----------------
  if (t < NR) dS[t] = deltas[brS[t]*TT + idxS[t]];
  #pragma unroll
  for (int k4 = 0; k4 < 18; ++k4) {
    float4 a = *(const float4*)(dW1 + t*HH + 4*k4);
    wcol[4*k4+0] = a.x; wcol[4*k4+1] = a.y; wcol[4*k4+2] = a.z; wcol[4*k4+3] = a.w;
  }
  load_wxz(dW1);
  const float dbias1 = db1[t], dbias2 = db1[j2];
  __syncthreads();

#define DPAIR(u, r) { \
    float d = dS[(r)]; \
    float sp = snapP[(r)][(u)], sc = snapC[(r)][(u)]; \
    float v = fmaf(d, sc - sp, sp); \
    hS[(u)][(r)] = v; hT[(r)][(u)] = v; }

  DPAIR(pu0, pr0);
  DPAIR(pu1, pr1);
  if (t < 64) DPAIR(pu2, pr2);
  __syncthreads();

  // layer1: 288 x 72
  {
    float acc[NR];
    #pragma unroll
    for (int r = 0; r < NR; ++r) acc[r] = dbias1;
    float acce = dbias2;
    #pragma unroll
    for (int k = 0; k < HH; ++k) { FMA8(acc, wcol[k], &hS[k][0]); }
    #pragma unroll
    for (int k4 = 0; k4 < 18; ++k4) {
      float4 wz = *(const float4*)&WxZ[(k4*32 + (t & 31))*4];
      float4 hv = *(const float4*)&hT[er][4*k4];
      acce = fmaf(wz.x, hv.x, acce);
      acce = fmaf(wz.y, hv.y, acce);
      acce = fmaf(wz.z, hv.z, acce);
      acce = fmaf(wz.w, hv.w, acce);
    }
    float* d1S = rnnS; // [k][8]
    #pragma unroll
    for (int r = 0; r < NR; ++r) { float v = ftanh(acc[r]); d1S[t*8 + r] = v; d1T[r][t] = v; }
    { float v = ftanh(acce); d1S[j2*8 + er] = v; d1T[er][j2] = v; }
  }
  __syncthreads();

  // layer2: 288 x 288, weights streamed from global (L1/L2 resident)
  {
    const float* d1S = rnnS;
    float acc[NR];
    float b = db2[t];
    #pragma unroll
    for (int r = 0; r < NR; ++r) acc[r] = b;
    float acce = db2[j2];
    const float4* w4a = (const float4*)(dW2 + t*288);
    const float4* w4b = (const float4*)(dW2 + j2*288);
    #pragma unroll 4
    for (int k4 = 0; k4 < 72; ++k4) {
      float4 w = w4a[k4];
      FMA8(acc, w.x, d1S + (4*k4+0)*8);
      FMA8(acc, w.y, d1S + (4*k4+1)*8);
      FMA8(acc, w.z, d1S + (4*k4+2)*8);
      FMA8(acc, w.w, d1S + (4*k4+3)*8);
      float4 we = w4b[k4];
      float4 hv = *(const float4*)&d1T[er][4*k4];
      acce = fmaf(we.x, hv.x, acce);
      acce = fmaf(we.y, hv.y, acce);
      acce = fmaf(we.z, hv.z, acce);
      acce = fmaf(we.w, hv.w, acce);
    }
    float* d2S = gS;   // [k][8]
    #pragma unroll
    for (int r = 0; r < NR; ++r) d2S[t*8 + r] = ftanh(acc[r]);
    d2S[j2*8 + er] = ftanh(acce);
  }
  __syncthreads();

  // layer3: 8 x 288 (linear) + scatter store
  if (t < 64) {
    const float* d2S = gS;
    int o = t & 7, r = t >> 3;
    float acc3 = db3[o];
    const float* wr = dW3 + o*288;
    #pragma unroll 4
    for (int k = 0; k < 288; ++k) acc3 = fmaf(wr[k], d2S[k*8 + r], acc3);
    out[brS[r]*8 + o] = acc3;
  }
}

extern "C" void kernel_launch(void* const* d_in, const int* in_sizes, int n_in,
                              void* d_out, int out_size, void* d_ws, size_t ws_size,
                              hipStream_t stream) {
  const float* x      = (const float*)d_in[0];
  const float* rnn    = (const float*)d_in[1];
  const float* deltas = (const float*)d_in[2];
  const int*   h_lens = (const int*)  d_in[3];
  const float* W_ih   = (const float*)d_in[4];
  const float* W_hh   = (const float*)d_in[5];
  const float* b_ih   = (const float*)d_in[6];
  const float* b_hh   = (const float*)d_in[7];
  const float* eW1    = (const float*)d_in[8];
  const float* eb1    = (const float*)d_in[9];
  const float* eW2    = (const float*)d_in[10];
  const float* eb2    = (const float*)d_in[11];
  const float* eW3    = (const float*)d_in[12];
  const float* eb3    = (const float*)d_in[13];
  const float* dW1    = (const float*)d_in[14];
  const float* db1    = (const float*)d_in[15];
  const float* dW2    = (const float*)d_in[16];
  const float* db2    = (const float*)d_in[17];
  const float* dW3    = (const float*)d_in[18];
  const float* db3    = (const float*)d_in[19];
  float* out = (float*)d_out;

  int* perm = nullptr;
  if (ws_size >= 2048 * sizeof(int)) {
    perm = (int*)d_ws;
    cfm_sort<<<1, NTH, 0, stream>>>(h_lens, perm);
  }
  cfm_main<<<2048/NR, NTH, 0, stream>>>(x, rnn, deltas, h_lens, W_ih, W_hh, b_ih, b_hh,
                                        eW1, eb1, eW2, eb2, eW3, eb3,
                                        dW1, db1, dW2, db2, dW3, db3,
                                        perm, out);
}

// Round 3
// 842.903 us; speedup vs baseline: 2.0583x; 2.0583x over previous
//
#include <hip/hip_runtime.h>
#include <cstdint>

#define HH 72
#define NR 8
#define NTH 256
#define TT 512

typedef __attribute__((ext_vector_type(8))) short short8;
typedef __attribute__((ext_vector_type(4))) float f32x4;

#if __has_builtin(__builtin_amdgcn_exp2f)
#define EXP2(x) __builtin_amdgcn_exp2f(x)
#else
#define EXP2(x) exp2f(x)
#endif
#if __has_builtin(__builtin_amdgcn_rcpf)
#define RCP(x) __builtin_amdgcn_rcpf(x)
#else
#define RCP(x) (1.0f/(x))
#endif

__device__ __forceinline__ float fsig(float x) {
  float e = EXP2(x * -1.442695040888963f);
  return RCP(1.0f + e);
}
__device__ __forceinline__ float ftanh(float x) {
  float e = EXP2(x * -2.885390081777927f);
  return fmaf(2.0f, RCP(1.0f + e), -1.0f);
}

// bf16 round-to-nearest-even of a finite float, returns low 16 bits
__device__ __forceinline__ unsigned bf16rne(float v) {
  unsigned b = __float_as_uint(v);
  return (b + 0x7FFFu + ((b >> 16) & 1u)) >> 16;
}
// pack hi|lo split: low16 = bf16(v), high16 = bf16(v - f32(hi))
__device__ __forceinline__ unsigned packHiLo(float v) {
  unsigned hi = bf16rne(v);
  float hf = __uint_as_float(hi << 16);
  unsigned lo = bf16rne(v - hf);
  return hi | (lo << 16);
}

// accumulate 8 rows: A[r] += W_ * P_[r]  (encoder/decoder use only)
#define FMA8(A, W_, P_) { \
  const float4 _fa = *(const float4*)(P_); \
  const float4 _fb = *(const float4*)(((const float*)(P_)) + 4); \
  A[0] = fmaf((W_), _fa.x, A[0]); A[1] = fmaf((W_), _fa.y, A[1]); \
  A[2] = fmaf((W_), _fa.z, A[2]); A[3] = fmaf((W_), _fa.w, A[3]); \
  A[4] = fmaf((W_), _fb.x, A[4]); A[5] = fmaf((W_), _fb.y, A[5]); \
  A[6] = fmaf((W_), _fb.z, A[6]); A[7] = fmaf((W_), _fb.w, A[7]); }

// counting sort of rows by h_lens so blocks get similar-length rows
__global__ void cfm_sort(const int* __restrict__ h_lens, int* __restrict__ perm) {
  __shared__ int hist[257];
  __shared__ int offs[257];
  const int t = threadIdx.x;
  for (int i = t; i < 257; i += NTH) hist[i] = 0;
  __syncthreads();
  for (int i = t; i < 2048; i += NTH) {
    int bkt = min(max(h_lens[i] - 256, 0), 256);
    atomicAdd(&hist[bkt], 1);
  }
  __syncthreads();
  if (t == 0) { int s = 0; for (int i = 0; i < 257; ++i) { offs[i] = s; s += hist[i]; } }
  __syncthreads();
  for (int i = t; i < 2048; i += NTH) {
    int bkt = min(max(h_lens[i] - 256, 0), 256);
    int pos = atomicAdd(&offs[bkt], 1);
    perm[pos] = i;
  }
}

// hxF word index: packed hi|lo bf16 of A=[h(72)|xt(9)|pad], fragment-ordered.
// (kt,q,m,j): k = kt*32 + q*8 + j, m = batch row 0..15.
// group stride 196 (= 192+4) decorrelates banks; kt stride 784 == 16 mod 32.
#define HXF(kt, q, m, j) (((kt)*4 + (q))*196 + (m)*12 + (j))

__global__ __launch_bounds__(NTH, 1)
void cfm_main(const float* __restrict__ x, const float* __restrict__ rnn,
              const float* __restrict__ deltas, const int* __restrict__ h_lens,
              const float* __restrict__ W_ih, const float* __restrict__ W_hh,
              const float* __restrict__ b_ih, const float* __restrict__ b_hh,
              const float* __restrict__ eW1, const float* __restrict__ eb1,
              const float* __restrict__ eW2, const float* __restrict__ eb2,
              const float* __restrict__ eW3, const float* __restrict__ eb3,
              const float* __restrict__ dW1, const float* __restrict__ db1,
              const float* __restrict__ dW2, const float* __restrict__ db2,
              const float* __restrict__ dW3, const float* __restrict__ db3,
              const int* __restrict__ perm, float* __restrict__ out)
{
  __shared__ __align__(16) unsigned hxF[2352];     // packed hi|lo A operand
  __shared__ __align__(16) float gS[3744];         // gates [n][m], stride 13; enc z1S / dec d2S (stride 8)
  __shared__ __align__(16) float rnnS[2304];       // rnn chunk [tc][r][k]; enc z2S / dec d1S
  __shared__ __align__(16) float d1T[NR][288];
  __shared__ __align__(16) float WxZ[2304];
  __shared__ __align__(16) float snapP[NR][HH];
  __shared__ __align__(16) float snapC[NR][HH];
  __shared__ __align__(16) float hS[HH][NR];       // decoder only
  __shared__ __align__(16) float hT[NR][80];       // decoder only
  __shared__ __align__(16) float xS[8][NR];
  __shared__ int brS[NR];
  __shared__ int idxS[NR];
  __shared__ float dS[NR];

  const int t  = threadIdx.x;
  const int bb = blockIdx.x;

  for (int i = t; i < 2352; i += NTH) hxF[i] = 0;   // zero incl. pad rows 8..15

  if (t < NR) {
    int row = perm ? perm[bb*NR + t] : (bb*NR + t);
    brS[t]  = row;
    idxS[t] = h_lens[row] - 1;   // in [255, 511]
  }
  __syncthreads();

  int maxIdx = idxS[0];
  #pragma unroll
  for (int r = 1; r < NR; ++r) maxIdx = max(maxIdx, idxS[r]);

  const int lane = t & 63;
  const int wv   = t >> 6;
  const int col  = lane & 15;     // A row m / C col n / B col n
  const int q_a  = lane >> 4;     // quad
  const int base = wv*4 + (wv < 2 ? wv : 2);   // tiles: w0:0-4 w1:5-9 w2:10-13 w3:14-17
  const int NT   = (wv < 2) ? 5 : 4;
  const int j2 = 256 + (t & 31);  // decoder extra col
  const int er = t >> 5;

  // elementwise unit ownership: p = r*72 + u, units {t, t+256, t+512(t<64)}
  const int pu0 = t % 72,         pr0 = t / 72;
  const int pu1 = (t + 256) % 72, pr1 = (t + 256) / 72;
  const int pu2 = 8 + t,          pr2 = 7;
  const int pidx0 = idxS[pr0];
  const int pidx1 = idxS[pr1];
  const int pidx2 = (t < 64) ? idxS[7] : 0;
  float pc0 = 0.f, pc1 = 0.f, pc2 = 0.f;

  // ---------------- encoder: 8 -> 256 -> 256 -> 64 ----------------
  if (t < 64) { int r = t >> 3, k = t & 7; xS[k][r] = x[brS[r]*8 + k]; }
  __syncthreads();

  float* z1S = gS;   // [k][8]
  {
    float acc[NR];
    float b = eb1[t];
    #pragma unroll
    for (int r = 0; r < NR; ++r) acc[r] = b;
    #pragma unroll
    for (int k = 0; k < 8; ++k) { float w = eW1[t*8 + k]; FMA8(acc, w, &xS[k][0]); }
    #pragma unroll
    for (int r = 0; r < NR; ++r) z1S[t*8 + r] = ftanh(acc[r]);
  }
  __syncthreads();
  float* z2S = rnnS; // [k][8]
  {
    float acc[NR];
    float b = eb2[t];
    #pragma unroll
    for (int r = 0; r < NR; ++r) acc[r] = b;
    const float4* w4 = (const float4*)(eW2 + t*256);
    #pragma unroll 4
    for (int k4 = 0; k4 < 64; ++k4) {
      float4 w = w4[k4];
      FMA8(acc, w.x, z1S + (4*k4+0)*8);
      FMA8(acc, w.y, z1S + (4*k4+1)*8);
      FMA8(acc, w.z, z1S + (4*k4+2)*8);
      FMA8(acc, w.w, z1S + (4*k4+3)*8);
    }
    #pragma unroll
    for (int r = 0; r < NR; ++r) z2S[t*8 + r] = ftanh(acc[r]);
  }
  __syncthreads();
  if (t < 64) {                       // h0 (linear) -> hxF k = 8+t
    float acc[NR];
    float b = eb3[t];
    #pragma unroll
    for (int r = 0; r < NR; ++r) acc[r] = b;
    const float4* w4 = (const float4*)(eW3 + t*256);
    #pragma unroll 4
    for (int k4 = 0; k4 < 64; ++k4) {
      float4 w = w4[k4];
      FMA8(acc, w.x, z2S + (4*k4+0)*8);
      FMA8(acc, w.y, z2S + (4*k4+1)*8);
      FMA8(acc, w.z, z2S + (4*k4+2)*8);
      FMA8(acc, w.w, z2S + (4*k4+3)*8);
    }
    int u = 8 + t, kt = u >> 5, qq = (u >> 3) & 3, jj = u & 7;
    #pragma unroll
    for (int r = 0; r < NR; ++r) hxF[HXF(kt, qq, r, jj)] = packHiLo(acc[r]);
  } else if (t < 128) {               // x part -> hxF k = 0..7
    int tt2 = t - 64; int r = tt2 >> 3, k = tt2 & 7;
    hxF[HXF(0, 0, r, k)] = packHiLo(xS[k][r]);
  }

  // ---------------- B fragments (weights) in registers ----------------
  // B[k][n]: n = col, k = kt*32 + q_a*8 + j ; from Wcat = [W_hh.T ; W_ih.T ; 0]
  short8 Bhi[5][3], Blo[5][3];
  float bias[5];
  #pragma unroll
  for (int i = 0; i < 5; ++i) {
    int ii = (i < NT) ? i : 0;
    int n = (base + ii)*16 + col;
    bias[i] = b_ih[n] + b_hh[n];
    #pragma unroll
    for (int kt = 0; kt < 3; ++kt) {
      unsigned h16[8], l16[8];
      #pragma unroll
      for (int j = 0; j < 8; ++j) {
        int k = kt*32 + q_a*8 + j;
        float v = 0.f;
        if (k < 72)      v = W_hh[n*HH + k];
        else if (k < 81) v = W_ih[n*9 + (k - 72)];
        unsigned hi = bf16rne(v);
        h16[j] = hi;
        l16[j] = bf16rne(v - __uint_as_float(hi << 16));
      }
      union { unsigned u[4]; short8 s; } ch, cl;
      #pragma unroll
      for (int d = 0; d < 4; ++d) {
        ch.u[d] = h16[2*d] | (h16[2*d+1] << 16);
        cl.u[d] = l16[2*d] | (l16[2*d+1] << 16);
      }
      Bhi[i][kt] = ch.s;
      Blo[i][kt] = cl.s;
    }
  }
  const int AW0 = q_a*196 + col*12;          // A-frag read base (kt adds 784)
  const int cw0 = (base*16 + col)*13 + q_a*4;

#define CELL(u_, r_, c_, idxv_) { \
    float ig = gS[(u_)*13 + (r_)]; \
    float fg = gS[((u_)+72)*13 + (r_)]; \
    float gg = gS[((u_)+144)*13 + (r_)]; \
    float og = gS[((u_)+216)*13 + (r_)]; \
    (c_) = fmaf(fsig(fg), (c_), fsig(ig)*ftanh(gg)); \
    float hv = fsig(og) * ftanh(c_); \
    int kt_ = (u_) >> 5, qq_ = ((u_) >> 3) & 3, jj_ = (u_) & 7; \
    hxF[HXF(kt_, qq_, (r_), jj_)] = packHiLo(hv); \
    if (step == (idxv_) - 1) snapP[(r_)][(u_)] = hv; \
    if (step == (idxv_))     snapC[(r_)][(u_)] = hv; }

  // ---------------- LSTM over time ----------------
  int step = 0;
  __syncthreads();
  for (int chunk = 0; chunk*32 <= maxIdx; ++chunk) {
    // stage 32 steps of rnn_input -> rnnS[tc][r][k]
    #pragma unroll
    for (int i = 0; i < 9; ++i) {
      int e = t + NTH*i;            // 0..2303
      int r = e / 288, pos = e % 288;
      int tc = pos / 9, kk = pos - tc*9;
      rnnS[tc*72 + r*9 + kk] = rnn[brS[r]*4608 + chunk*288 + pos];
    }
    __syncthreads();
    if (t < 72) {                   // xt for first step of chunk
      int r = t / 9, kk = t - r*9;
      int qq = 1 + (kk >> 3), jj = kk & 7;
      hxF[(8 + qq)*196 + r*12 + jj] = packHiLo(rnnS[t]);
    }
    __syncthreads();
    int lim = min(31, maxIdx - chunk*32);
    for (int tc = 0; tc <= lim; ++tc, ++step) {
      // ---- phase 1: gates = [h|xt] @ Wcat.T + bias via MFMA (bf16x3 split)
      f32x4 acc[5];
      #pragma unroll
      for (int i = 0; i < 5; ++i) { acc[i].x = bias[i]; acc[i].y = bias[i]; acc[i].z = bias[i]; acc[i].w = bias[i]; }
      #pragma unroll
      for (int kt = 0; kt < 3; ++kt) {
        const unsigned* hp = &hxF[AW0 + kt*784];
        uint4 w0 = *(const uint4*)(hp);
        uint4 w1 = *(const uint4*)(hp + 4);
        union { unsigned u[4]; short8 s; } ah, al;
        ah.u[0] = __builtin_amdgcn_perm(w0.y, w0.x, 0x05040100u);
        ah.u[1] = __builtin_amdgcn_perm(w0.w, w0.z, 0x05040100u);
        ah.u[2] = __builtin_amdgcn_perm(w1.y, w1.x, 0x05040100u);
        ah.u[3] = __builtin_amdgcn_perm(w1.w, w1.z, 0x05040100u);
        al.u[0] = __builtin_amdgcn_perm(w0.y, w0.x, 0x07060302u);
        al.u[1] = __builtin_amdgcn_perm(w0.w, w0.z, 0x07060302u);
        al.u[2] = __builtin_amdgcn_perm(w1.y, w1.x, 0x07060302u);
        al.u[3] = __builtin_amdgcn_perm(w1.w, w1.z, 0x07060302u);
        short8 ahi = ah.s, alo = al.s;
        #pragma unroll
        for (int i = 0; i < 5; ++i) {
          if (i < NT) {
            acc[i] = __builtin_amdgcn_mfma_f32_16x16x32_bf16(ahi, Bhi[i][kt], acc[i], 0, 0, 0);
            acc[i] = __builtin_amdgcn_mfma_f32_16x16x32_bf16(alo, Bhi[i][kt], acc[i], 0, 0, 0);
            acc[i] = __builtin_amdgcn_mfma_f32_16x16x32_bf16(ahi, Blo[i][kt], acc[i], 0, 0, 0);
          }
        }
      }
      // C rows 0..7 live in lanes with q_a<2 (row = q_a*4 + reg)
      if (q_a < 2) {
        int cw = cw0;
        #pragma unroll
        for (int i = 0; i < 5; ++i) {
          if (i < NT) {
            gS[cw+0] = acc[i].x; gS[cw+1] = acc[i].y;
            gS[cw+2] = acc[i].z; gS[cw+3] = acc[i].w;
          }
          cw += 208;
        }
      }
      __syncthreads();
      // ---- phase 3: cell update + write h (and next xt) into hxF
      CELL(pu0, pr0, pc0, pidx0);
      CELL(pu1, pr1, pc1, pidx1);
      if (t < 64) CELL(pu2, pr2, pc2, pidx2);
      if (tc < 31 && t < 72) {
        int r = t / 9, kk = t - r*9;
        int qq = 1 + (kk >> 3), jj = kk & 7;
        hxF[(8 + qq)*196 + r*12 + jj] = packHiLo(rnnS[(tc+1)*72 + t]);
      }
      __syncthreads();
    }
  }

  // ---------------- decoder: 72 -> 288 -> 288 -> 8 ----------------
  if (t < NR) dS[t] = deltas[brS[t]*TT + idxS[t]];
  float wcol[HH];
  #pragma unroll
  for (int k4 = 0; k4 < 18; ++k4) {
    float4 a = *(const float4*)(dW1 + t*HH + 4*k4);
    wcol[4*k4+0] = a.x; wcol[4*k4+1] = a.y; wcol[4*k4+2] = a.z; wcol[4*k4+3] = a.w;
  }
  {
    #pragma unroll
    for (int i = 0; i < 9; ++i) {
      int e = t + NTH*i;            // 0..2303
      int j32 = e / 72, k = e % 72;
      WxZ[(k >> 2)*128 + j32*4 + (k & 3)] = dW1[(256 + j32)*HH + k];
    }
  }
  const float dbias1 = db1[t], dbias2 = db1[j2];
  __syncthreads();

#define DPAIR(u, r) { \
    float d = dS[(r)]; \
    float sp = snapP[(r)][(u)], sc = snapC[(r)][(u)]; \
    float v = fmaf(d, sc - sp, sp); \
    hS[(u)][(r)] = v; hT[(r)][(u)] = v; }

  DPAIR(pu0, pr0);
  DPAIR(pu1, pr1);
  if (t < 64) DPAIR(pu2, pr2);
  __syncthreads();

  // layer1: 288 x 72
  {
    float acc[NR];
    #pragma unroll
    for (int r = 0; r < NR; ++r) acc[r] = dbias1;
    float acce = dbias2;
    #pragma unroll
    for (int k = 0; k < HH; ++k) { FMA8(acc, wcol[k], &hS[k][0]); }
    #pragma unroll
    for (int k4 = 0; k4 < 18; ++k4) {
      float4 wz = *(const float4*)&WxZ[(k4*32 + (t & 31))*4];
      float4 hv = *(const float4*)&hT[er][4*k4];
      acce = fmaf(wz.x, hv.x, acce);
      acce = fmaf(wz.y, hv.y, acce);
      acce = fmaf(wz.z, hv.z, acce);
      acce = fmaf(wz.w, hv.w, acce);
    }
    float* d1S = rnnS; // [k][8]
    #pragma unroll
    for (int r = 0; r < NR; ++r) { float v = ftanh(acc[r]); d1S[t*8 + r] = v; d1T[r][t] = v; }
    { float v = ftanh(acce); d1S[j2*8 + er] = v; d1T[er][j2] = v; }
  }
  __syncthreads();

  // layer2: 288 x 288, weights streamed from global
  {
    const float* d1S = rnnS;
    float acc[NR];
    float b = db2[t];
    #pragma unroll
    for (int r = 0; r < NR; ++r) acc[r] = b;
    float acce = db2[j2];
    const float4* w4a = (const float4*)(dW2 + t*288);
    const float4* w4b = (const float4*)(dW2 + j2*288);
    #pragma unroll 4
    for (int k4 = 0; k4 < 72; ++k4) {
      float4 w = w4a[k4];
      FMA8(acc, w.x, d1S + (4*k4+0)*8);
      FMA8(acc, w.y, d1S + (4*k4+1)*8);
      FMA8(acc, w.z, d1S + (4*k4+2)*8);
      FMA8(acc, w.w, d1S + (4*k4+3)*8);
      float4 we = w4b[k4];
      float4 hv = *(const float4*)&d1T[er][4*k4];
      acce = fmaf(we.x, hv.x, acce);
      acce = fmaf(we.y, hv.y, acce);
      acce = fmaf(we.z, hv.z, acce);
      acce = fmaf(we.w, hv.w, acce);
    }
    float* d2S = gS;   // [k][8]
    #pragma unroll
    for (int r = 0; r < NR; ++r) d2S[t*8 + r] = ftanh(acc[r]);
    d2S[j2*8 + er] = ftanh(acce);
  }
  __syncthreads();

  // layer3: 8 x 288 (linear) + scatter store
  if (t < 64) {
    const float* d2S = gS;
    int o = t & 7, r = t >> 3;
    float acc3 = db3[o];
    const float* wr = dW3 + o*288;
    #pragma unroll 4
    for (int k = 0; k < 288; ++k) acc3 = fmaf(wr[k], d2S[k*8 + r], acc3);
    out[brS[r]*8 + o] = acc3;
  }
}

extern "C" void kernel_launch(void* const* d_in, const int* in_sizes, int n_in,
                              void* d_out, int out_size, void* d_ws, size_t ws_size,
                              hipStream_t stream) {
  const float* x      = (const float*)d_in[0];
  const float* rnn    = (const float*)d_in[1];
  const float* deltas = (const float*)d_in[2];
  const int*   h_lens = (const int*)  d_in[3];
  const float* W_ih   = (const float*)d_in[4];
  const float* W_hh   = (const float*)d_in[5];
  const float* b_ih   = (const float*)d_in[6];
  const float* b_hh   = (const float*)d_in[7];
  const float* eW1    = (const float*)d_in[8];
  const float* eb1    = (const float*)d_in[9];
  const float* eW2    = (const float*)d_in[10];
  const float* eb2    = (const float*)d_in[11];
  const float* eW3    = (const float*)d_in[12];
  const float* eb3    = (const float*)d_in[13];
  const float* dW1    = (const float*)d_in[14];
  const float* db1    = (const float*)d_in[15];
  const float* dW2    = (const float*)d_in[16];
  const float* db2    = (const float*)d_in[17];
  const float* dW3    = (const float*)d_in[18];
  const float* db3    = (const float*)d_in[19];
  float* out = (float*)d_out;

  int* perm = nullptr;
  if (ws_size >= 2048 * sizeof(int)) {
    perm = (int*)d_ws;
    cfm_sort<<<1, NTH, 0, stream>>>(h_lens, perm);
  }
  cfm_main<<<2048/NR, NTH, 0, stream>>>(x, rnn, deltas, h_lens, W_ih, W_hh, b_ih, b_hh,
                                        eW1, eb1, eW2, eb2, eW3, eb3,
                                        dW1, db1, dW2, db2, dW3, db3,
                                        perm, out);
}

// Round 4
// 774.382 us; speedup vs baseline: 2.2404x; 1.0885x over previous
//
#include <hip/hip_runtime.h>
#include <cstdint>

#define HH 72
#define NR 8
#define NTH 256
#define TT 512

typedef __attribute__((ext_vector_type(8))) short short8;
typedef __attribute__((ext_vector_type(4))) float f32x4;

#if __has_builtin(__builtin_amdgcn_exp2f)
#define EXP2(x) __builtin_amdgcn_exp2f(x)
#else
#define EXP2(x) exp2f(x)
#endif
#if __has_builtin(__builtin_amdgcn_rcpf)
#define RCP(x) __builtin_amdgcn_rcpf(x)
#else
#define RCP(x) (1.0f/(x))
#endif

__device__ __forceinline__ float fsig(float x) {
  float e = EXP2(x * -1.442695040888963f);
  return RCP(1.0f + e);
}
__device__ __forceinline__ float ftanh(float x) {
  float e = EXP2(x * -2.885390081777927f);
  return fmaf(2.0f, RCP(1.0f + e), -1.0f);
}

// bf16 round-to-nearest-even of a finite float, returns low 16 bits
__device__ __forceinline__ unsigned bf16rne(float v) {
  unsigned b = __float_as_uint(v);
  return (b + 0x7FFFu + ((b >> 16) & 1u)) >> 16;
}
// pack hi|lo split: low16 = bf16(v), high16 = bf16(v - f32(hi))
__device__ __forceinline__ unsigned packHiLo(float v) {
  unsigned hi = bf16rne(v);
  float hf = __uint_as_float(hi << 16);
  unsigned lo = bf16rne(v - hf);
  return hi | (lo << 16);
}

// B-fragment ushort index for value at contraction-dim k, batch col m.
// Layout [kt*4+q][m][8] : 8 contiguous ushorts per (group, m) -> ds_read_b128.
__device__ __forceinline__ int bidx(int k, int m) {
  return ((k >> 5)*4 + ((k >> 3) & 3))*128 + m*8 + (k & 7);
}

// accumulate 8 rows: A[r] += W_ * P_[r]  (encoder/decoder use only)
#define FMA8(A, W_, P_) { \
  const float4 _fa = *(const float4*)(P_); \
  const float4 _fb = *(const float4*)(((const float*)(P_)) + 4); \
  A[0] = fmaf((W_), _fa.x, A[0]); A[1] = fmaf((W_), _fa.y, A[1]); \
  A[2] = fmaf((W_), _fa.z, A[2]); A[3] = fmaf((W_), _fa.w, A[3]); \
  A[4] = fmaf((W_), _fb.x, A[4]); A[5] = fmaf((W_), _fb.y, A[5]); \
  A[6] = fmaf((W_), _fb.z, A[6]); A[7] = fmaf((W_), _fb.w, A[7]); }

// counting sort of rows by h_lens so blocks get similar-length rows
__global__ void cfm_sort(const int* __restrict__ h_lens, int* __restrict__ perm) {
  __shared__ int hist[257];
  __shared__ int offs[257];
  const int t = threadIdx.x;
  for (int i = t; i < 257; i += NTH) hist[i] = 0;
  __syncthreads();
  for (int i = t; i < 2048; i += NTH) {
    int bkt = min(max(h_lens[i] - 256, 0), 256);
    atomicAdd(&hist[bkt], 1);
  }
  __syncthreads();
  if (t == 0) { int s = 0; for (int i = 0; i < 257; ++i) { offs[i] = s; s += hist[i]; } }
  __syncthreads();
  for (int i = t; i < 2048; i += NTH) {
    int bkt = min(max(h_lens[i] - 256, 0), 256);
    int pos = atomicAdd(&offs[bkt], 1);
    perm[pos] = i;
  }
}

__global__ __launch_bounds__(NTH, 1)
void cfm_main(const float* __restrict__ x, const float* __restrict__ rnn,
              const float* __restrict__ deltas, const int* __restrict__ h_lens,
              const float* __restrict__ W_ih, const float* __restrict__ W_hh,
              const float* __restrict__ b_ih, const float* __restrict__ b_hh,
              const float* __restrict__ eW1, const float* __restrict__ eb1,
              const float* __restrict__ eW2, const float* __restrict__ eb2,
              const float* __restrict__ eW3, const float* __restrict__ eb3,
              const float* __restrict__ dW1, const float* __restrict__ db1,
              const float* __restrict__ dW2, const float* __restrict__ db2,
              const float* __restrict__ dW3, const float* __restrict__ db3,
              const int* __restrict__ perm, float* __restrict__ out)
{
  // double-buffered bf16 hi/lo B-fragment arrays for [h(72)|xt(9)|pad] x 16 batch cols
  __shared__ __align__(16) unsigned short bHiS[2][1536];
  __shared__ __align__(16) unsigned short bLoS[2][1536];
  __shared__ __align__(16) float gS[2304];         // enc z1S / dec d2S
  __shared__ __align__(16) float rnnS[2304];       // rnn chunk [tc][r][k]; enc z2S / dec d1S
  __shared__ __align__(16) float d1T[NR][288];
  __shared__ __align__(16) float WxZ[2304];
  __shared__ __align__(16) float snapP[NR][HH];
  __shared__ __align__(16) float snapC[NR][HH];
  __shared__ __align__(16) float hS[HH][NR];       // decoder only
  __shared__ __align__(16) float hT[NR][80];       // decoder only
  __shared__ __align__(16) float xS[8][NR];
  __shared__ int brS[NR];
  __shared__ int idxS[NR];
  __shared__ float dS[NR];

  const int t  = threadIdx.x;
  const int bb = blockIdx.x;

  // zero both buffers (padding k=81..95 and cols m=8..15 must stay zero)
  for (int i = t; i < 1536; i += NTH) { ((unsigned*)bHiS)[i] = 0; ((unsigned*)bLoS)[i] = 0; }

  if (t < NR) {
    int row = perm ? perm[bb*NR + t] : (bb*NR + t);
    brS[t]  = row;
    idxS[t] = h_lens[row] - 1;   // in [255, 511]
  }
  __syncthreads();

  int maxIdx = idxS[0];
  #pragma unroll
  for (int r = 1; r < NR; ++r) maxIdx = max(maxIdx, idxS[r]);

  const int lane = t & 63;
  const int wv   = t >> 6;
  const int col  = lane & 15;     // C col = batch row ; A row index within tile
  const int q_a  = lane >> 4;     // quad
  const int base = wv*4 + (wv < 2 ? wv : 2);   // tiles: w0:0-4 w1:5-9 w2:10-13 w3:14-17
  const int NT   = (wv < 2) ? 5 : 4;
  const int j2 = 256 + (t & 31);  // decoder extra col
  const int er = t >> 5;

  // decoder elementwise ownership: p = r*72 + u, units {t, t+256, t+512(t<64)}
  const int pu0 = t % 72,         pr0 = t / 72;
  const int pu1 = (t + 256) % 72, pr1 = (t + 256) / 72;
  const int pu2 = 8 + t,          pr2 = 7;

  // cell ownership: lane (q_a, col<8) owns units u = 4*(base+i)+q_a, batch col
  const int cidx = (col < 8) ? idxS[col] : -1000000;
  float cst[5] = {0.f, 0.f, 0.f, 0.f, 0.f};

  // ---------------- encoder: 8 -> 256 -> 256 -> 64 ----------------
  if (t < 64) { int r = t >> 3, k = t & 7; xS[k][r] = x[brS[r]*8 + k]; }
  __syncthreads();

  float* z1S = gS;   // [k][8]
  {
    float acc[NR];
    float b = eb1[t];
    #pragma unroll
    for (int r = 0; r < NR; ++r) acc[r] = b;
    #pragma unroll
    for (int k = 0; k < 8; ++k) { float w = eW1[t*8 + k]; FMA8(acc, w, &xS[k][0]); }
    #pragma unroll
    for (int r = 0; r < NR; ++r) z1S[t*8 + r] = ftanh(acc[r]);
  }
  __syncthreads();
  float* z2S = rnnS; // [k][8]
  {
    float acc[NR];
    float b = eb2[t];
    #pragma unroll
    for (int r = 0; r < NR; ++r) acc[r] = b;
    const float4* w4 = (const float4*)(eW2 + t*256);
    #pragma unroll 4
    for (int k4 = 0; k4 < 64; ++k4) {
      float4 w = w4[k4];
      FMA8(acc, w.x, z1S + (4*k4+0)*8);
      FMA8(acc, w.y, z1S + (4*k4+1)*8);
      FMA8(acc, w.z, z1S + (4*k4+2)*8);
      FMA8(acc, w.w, z1S + (4*k4+3)*8);
    }
    #pragma unroll
    for (int r = 0; r < NR; ++r) z2S[t*8 + r] = ftanh(acc[r]);
  }
  __syncthreads();
  if (t < 64) {                       // h0 (linear) -> B-frag k = 8+t, buffer 0
    float acc[NR];
    float b = eb3[t];
    #pragma unroll
    for (int r = 0; r < NR; ++r) acc[r] = b;
    const float4* w4 = (const float4*)(eW3 + t*256);
    #pragma unroll 4
    for (int k4 = 0; k4 < 64; ++k4) {
      float4 w = w4[k4];
      FMA8(acc, w.x, z2S + (4*k4+0)*8);
      FMA8(acc, w.y, z2S + (4*k4+1)*8);
      FMA8(acc, w.z, z2S + (4*k4+2)*8);
      FMA8(acc, w.w, z2S + (4*k4+3)*8);
    }
    int u = 8 + t;
    #pragma unroll
    for (int r = 0; r < NR; ++r) {
      unsigned p = packHiLo(acc[r]);
      int id = bidx(u, r);
      bHiS[0][id] = (unsigned short)p;
      bLoS[0][id] = (unsigned short)(p >> 16);
    }
  } else if (t < 128) {               // x part -> k = 0..7, buffer 0
    int tt2 = t - 64; int r = tt2 >> 3, k = tt2 & 7;
    unsigned p = packHiLo(xS[k][r]);
    int id = bidx(k, r);
    bHiS[0][id] = (unsigned short)p;
    bLoS[0][id] = (unsigned short)(p >> 16);
  }

  // ---------------- weights as A-fragments (gate-permuted rows) ----------------
  // n' = 4*unit + gate ; source row = gate*72 + unit. A[m=n'][k], k = kt*32+q_a*8+j.
  short8 Ahi[5][3], Alo[5][3];
  f32x4 biasq[5];
  #pragma unroll
  for (int i = 0; i < 5; ++i) {
    int ii = (i < NT) ? i : 0;
    int u = 4*(base + ii) + q_a;        // unit owned for C rows of this tile
    biasq[i].x = b_ih[u]       + b_hh[u];
    biasq[i].y = b_ih[72 + u]  + b_hh[72 + u];
    biasq[i].z = b_ih[144 + u] + b_hh[144 + u];
    biasq[i].w = b_ih[216 + u] + b_hh[216 + u];
    int nprime = (base + ii)*16 + col;
    int srcrow = (nprime & 3)*72 + (nprime >> 2);
    #pragma unroll
    for (int kt = 0; kt < 3; ++kt) {
      unsigned h16[8], l16[8];
      #pragma unroll
      for (int j = 0; j < 8; ++j) {
        int k = kt*32 + q_a*8 + j;
        float v = 0.f;
        if (k < 72)      v = W_hh[srcrow*HH + k];
        else if (k < 81) v = W_ih[srcrow*9 + (k - 72)];
        unsigned hi = bf16rne(v);
        h16[j] = hi;
        l16[j] = bf16rne(v - __uint_as_float(hi << 16));
      }
      union { unsigned u4[4]; short8 s; } ch, cl;
      #pragma unroll
      for (int d = 0; d < 4; ++d) {
        ch.u4[d] = h16[2*d] | (h16[2*d+1] << 16);
        cl.u4[d] = l16[2*d] | (l16[2*d+1] << 16);
      }
      Ahi[i][kt] = ch.s;
      Alo[i][kt] = cl.s;
    }
  }

  // ---------------- LSTM over time: ONE barrier per step ----------------
  int step = 0;
  int par = 0;
  __syncthreads();
  for (int chunk = 0; chunk*32 <= maxIdx; ++chunk) {
    // stage 32 steps of rnn_input -> rnnS[tc][r][k]
    #pragma unroll
    for (int i = 0; i < 9; ++i) {
      int e = t + NTH*i;            // 0..2303
      int r = e / 288, pos = e % 288;
      int tc = pos / 9, kk = pos - tc*9;
      rnnS[tc*72 + r*9 + kk] = rnn[brS[r]*4608 + chunk*288 + pos];
    }
    __syncthreads();
    if (t < 72) {                   // xt for first step of chunk -> buffer par(==0)
      int r = t / 9, kk = t - r*9;
      unsigned p = packHiLo(rnnS[t]);
      int id = bidx(72 + kk, r);
      bHiS[par][id] = (unsigned short)p;
      bLoS[par][id] = (unsigned short)(p >> 16);
    }
    __syncthreads();
    int lim = min(31, maxIdx - chunk*32);
    for (int tc = 0; tc <= lim; ++tc, ++step) {
      const int np = par ^ 1;
      // gates^T = Wcat (A) x [h|xt] (B), bf16x3 split, C[n'][m]
      f32x4 acc[5];
      #pragma unroll
      for (int i = 0; i < 5; ++i) acc[i] = biasq[i];
      #pragma unroll
      for (int kt = 0; kt < 3; ++kt) {
        int rb = (kt*4 + q_a)*128 + col*8;
        short8 bh = *(const short8*)&bHiS[par][rb];
        short8 bl = *(const short8*)&bLoS[par][rb];
        #pragma unroll
        for (int i = 0; i < 5; ++i) {
          if (i < NT) {
            acc[i] = __builtin_amdgcn_mfma_f32_16x16x32_bf16(Ahi[i][kt], bh, acc[i], 0, 0, 0);
            acc[i] = __builtin_amdgcn_mfma_f32_16x16x32_bf16(Alo[i][kt], bh, acc[i], 0, 0, 0);
            acc[i] = __builtin_amdgcn_mfma_f32_16x16x32_bf16(Ahi[i][kt], bl, acc[i], 0, 0, 0);
          }
        }
      }
      // in-register cell update: lane (q_a, col<8), acc[i] = {i,f,g,o} of unit u
      if (col < 8) {
        #pragma unroll
        for (int i = 0; i < 5; ++i) {
          if (i < NT) {
            int u = 4*(base + i) + q_a;
            float ig = acc[i].x, fg = acc[i].y, gg = acc[i].z, og = acc[i].w;
            cst[i] = fmaf(fsig(fg), cst[i], fsig(ig)*ftanh(gg));
            float hv = fsig(og) * ftanh(cst[i]);
            unsigned p = packHiLo(hv);
            int id = bidx(u, col);
            bHiS[np][id] = (unsigned short)p;
            bLoS[np][id] = (unsigned short)(p >> 16);
            if (step == cidx - 1) snapP[col][u] = hv;
            if (step == cidx)     snapC[col][u] = hv;
          }
        }
      }
      if (tc < 31 && t < 72) {      // xt for next step -> buffer np
        int r = t / 9, kk = t - r*9;
        unsigned p = packHiLo(rnnS[(tc+1)*72 + t]);
        int id = bidx(72 + kk, r);
        bHiS[np][id] = (unsigned short)p;
        bLoS[np][id] = (unsigned short)(p >> 16);
      }
      __syncthreads();
      par = np;
    }
  }

  // ---------------- decoder: 72 -> 288 -> 288 -> 8 ----------------
  if (t < NR) dS[t] = deltas[brS[t]*TT + idxS[t]];
  float wcol[HH];
  #pragma unroll
  for (int k4 = 0; k4 < 18; ++k4) {
    float4 a = *(const float4*)(dW1 + t*HH + 4*k4);
    wcol[4*k4+0] = a.x; wcol[4*k4+1] = a.y; wcol[4*k4+2] = a.z; wcol[4*k4+3] = a.w;
  }
  {
    #pragma unroll
    for (int i = 0; i < 9; ++i) {
      int e = t + NTH*i;            // 0..2303
      int j32 = e / 72, k = e % 72;
      WxZ[(k >> 2)*128 + j32*4 + (k & 3)] = dW1[(256 + j32)*HH + k];
    }
  }
  const float dbias1 = db1[t], dbias2 = db1[j2];
  __syncthreads();

#define DPAIR(u, r) { \
    float d = dS[(r)]; \
    float sp = snapP[(r)][(u)], sc = snapC[(r)][(u)]; \
    float v = fmaf(d, sc - sp, sp); \
    hS[(u)][(r)] = v; hT[(r)][(u)] = v; }

  DPAIR(pu0, pr0);
  DPAIR(pu1, pr1);
  if (t < 64) DPAIR(pu2, pr2);
  __syncthreads();

  // layer1: 288 x 72
  {
    float acc[NR];
    #pragma unroll
    for (int r = 0; r < NR; ++r) acc[r] = dbias1;
    float acce = dbias2;
    #pragma unroll
    for (int k = 0; k < HH; ++k) { FMA8(acc, wcol[k], &hS[k][0]); }
    #pragma unroll
    for (int k4 = 0; k4 < 18; ++k4) {
      float4 wz = *(const float4*)&WxZ[(k4*32 + (t & 31))*4];
      float4 hv = *(const float4*)&hT[er][4*k4];
      acce = fmaf(wz.x, hv.x, acce);
      acce = fmaf(wz.y, hv.y, acce);
      acce = fmaf(wz.z, hv.z, acce);
      acce = fmaf(wz.w, hv.w, acce);
    }
    float* d1S = rnnS; // [k][8]
    #pragma unroll
    for (int r = 0; r < NR; ++r) { float v = ftanh(acc[r]); d1S[t*8 + r] = v; d1T[r][t] = v; }
    { float v = ftanh(acce); d1S[j2*8 + er] = v; d1T[er][j2] = v; }
  }
  __syncthreads();

  // layer2: 288 x 288, weights streamed from global
  {
    const float* d1S = rnnS;
    float acc[NR];
    float b = db2[t];
    #pragma unroll
    for (int r = 0; r < NR; ++r) acc[r] = b;
    float acce = db2[j2];
    const float4* w4a = (const float4*)(dW2 + t*288);
    const float4* w4b = (const float4*)(dW2 + j2*288);
    #pragma unroll 4
    for (int k4 = 0; k4 < 72; ++k4) {
      float4 w = w4a[k4];
      FMA8(acc, w.x, d1S + (4*k4+0)*8);
      FMA8(acc, w.y, d1S + (4*k4+1)*8);
      FMA8(acc, w.z, d1S + (4*k4+2)*8);
      FMA8(acc, w.w, d1S + (4*k4+3)*8);
      float4 we = w4b[k4];
      float4 hv = *(const float4*)&d1T[er][4*k4];
      acce = fmaf(we.x, hv.x, acce);
      acce = fmaf(we.y, hv.y, acce);
      acce = fmaf(we.z, hv.z, acce);
      acce = fmaf(we.w, hv.w, acce);
    }
    float* d2S = gS;   // [k][8]
    #pragma unroll
    for (int r = 0; r < NR; ++r) d2S[t*8 + r] = ftanh(acc[r]);
    d2S[j2*8 + er] = ftanh(acce);
  }
  __syncthreads();

  // layer3: 8 x 288 (linear) + scatter store
  if (t < 64) {
    const float* d2S = gS;
    int o = t & 7, r = t >> 3;
    float acc3 = db3[o];
    const float* wr = dW3 + o*288;
    #pragma unroll 4
    for (int k = 0; k < 288; ++k) acc3 = fmaf(wr[k], d2S[k*8 + r], acc3);
    out[brS[r]*8 + o] = acc3;
  }
}

extern "C" void kernel_launch(void* const* d_in, const int* in_sizes, int n_in,
                              void* d_out, int out_size, void* d_ws, size_t ws_size,
                              hipStream_t stream) {
  const float* x      = (const float*)d_in[0];
  const float* rnn    = (const float*)d_in[1];
  const float* deltas = (const float*)d_in[2];
  const int*   h_lens = (const int*)  d_in[3];
  const float* W_ih   = (const float*)d_in[4];
  const float* W_hh   = (const float*)d_in[5];
  const float* b_ih   = (const float*)d_in[6];
  const float* b_hh   = (const float*)d_in[7];
  const float* eW1    = (const float*)d_in[8];
  const float* eb1    = (const float*)d_in[9];
  const float* eW2    = (const float*)d_in[10];
  const float* eb2    = (const float*)d_in[11];
  const float* eW3    = (const float*)d_in[12];
  const float* eb3    = (const float*)d_in[13];
  const float* dW1    = (const float*)d_in[14];
  const float* db1    = (const float*)d_in[15];
  const float* dW2    = (const float*)d_in[16];
  const float* db2    = (const float*)d_in[17];
  const float* dW3    = (const float*)d_in[18];
  const float* db3    = (const float*)d_in[19];
  float* out = (float*)d_out;

  int* perm = nullptr;
  if (ws_size >= 2048 * sizeof(int)) {
    perm = (int*)d_ws;
    cfm_sort<<<1, NTH, 0, stream>>>(h_lens, perm);
  }
  cfm_main<<<2048/NR, NTH, 0, stream>>>(x, rnn, deltas, h_lens, W_ih, W_hh, b_ih, b_hh,
                                        eW1, eb1, eW2, eb2, eW3, eb3,
                                        dW1, db1, dW2, db2, dW3, db3,
                                        perm, out);
}

// Round 6
// 559.197 us; speedup vs baseline: 3.1026x; 1.3848x over previous
//
#include <hip/hip_runtime.h>
#include <cstdint>

#define HH 72
#define NR 8
#define NTH 512
#define TT 512

typedef __attribute__((ext_vector_type(8))) short short8;
typedef __attribute__((ext_vector_type(4))) float f32x4;

#if __has_builtin(__builtin_amdgcn_exp2f)
#define EXP2(x) __builtin_amdgcn_exp2f(x)
#else
#define EXP2(x) exp2f(x)
#endif
#if __has_builtin(__builtin_amdgcn_rcpf)
#define RCP(x) __builtin_amdgcn_rcpf(x)
#else
#define RCP(x) (1.0f/(x))
#endif

__device__ __forceinline__ float fsig(float x) {
  float e = EXP2(x * -1.442695040888963f);
  return RCP(1.0f + e);
}
__device__ __forceinline__ float ftanh(float x) {
  float e = EXP2(x * -2.885390081777927f);
  return fmaf(2.0f, RCP(1.0f + e), -1.0f);
}

__device__ __forceinline__ unsigned bf16rne(float v) {
  unsigned b = __float_as_uint(v);
  return (b + 0x7FFFu + ((b >> 16) & 1u)) >> 16;
}
__device__ __forceinline__ unsigned packHiLo(float v) {
  unsigned hi = bf16rne(v);
  float hf = __uint_as_float(hi << 16);
  unsigned lo = bf16rne(v - hf);
  return hi | (lo << 16);
}

// B-fragment ushort index for contraction-dim k, batch col m.
// Layout [kt*4+q][m][8]: 8 contiguous ushorts -> ds_read_b128 per (group,m).
__device__ __forceinline__ int bidx(int k, int m) {
  return ((k >> 5)*4 + ((k >> 3) & 3))*128 + m*8 + (k & 7);
}

// lane^8 swizzle (BitMode: xor=8, and=0x1F)
__device__ __forceinline__ float swz8(float v) {
  return __int_as_float(__builtin_amdgcn_ds_swizzle(__float_as_int(v), 0x201F));
}

__device__ __forceinline__ float cellUpd(float ig, float fg, float gg, float og, float& c) {
  c = fmaf(fsig(fg), c, fsig(ig)*ftanh(gg));
  return fsig(og)*ftanh(c);
}

// accumulate 8 rows: A[r] += W_ * P_[r]
#define FMA8(A, W_, P_) { \
  const float4 _fa = *(const float4*)(P_); \
  const float4 _fb = *(const float4*)(((const float*)(P_)) + 4); \
  A[0] = fmaf((W_), _fa.x, A[0]); A[1] = fmaf((W_), _fa.y, A[1]); \
  A[2] = fmaf((W_), _fa.z, A[2]); A[3] = fmaf((W_), _fa.w, A[3]); \
  A[4] = fmaf((W_), _fb.x, A[4]); A[5] = fmaf((W_), _fb.y, A[5]); \
  A[6] = fmaf((W_), _fb.z, A[6]); A[7] = fmaf((W_), _fb.w, A[7]); }

// counting sort of rows by h_lens so blocks get similar-length rows
__global__ void cfm_sort(const int* __restrict__ h_lens, int* __restrict__ perm) {
  __shared__ int hist[257];
  __shared__ int offs[257];
  const int t = threadIdx.x; // 256
  for (int i = t; i < 257; i += 256) hist[i] = 0;
  __syncthreads();
  for (int i = t; i < 2048; i += 256) {
    int bkt = min(max(h_lens[i] - 256, 0), 256);
    atomicAdd(&hist[bkt], 1);
  }
  __syncthreads();
  if (t == 0) { int s = 0; for (int i = 0; i < 257; ++i) { offs[i] = s; s += hist[i]; } }
  __syncthreads();
  for (int i = t; i < 2048; i += 256) {
    int bkt = min(max(h_lens[i] - 256, 0), 256);
    int pos = atomicAdd(&offs[bkt], 1);
    perm[pos] = i;
  }
}

__global__ __launch_bounds__(NTH, 2)
void cfm_main(const float* __restrict__ x, const float* __restrict__ rnn,
              const float* __restrict__ deltas, const int* __restrict__ h_lens,
              const float* __restrict__ W_ih, const float* __restrict__ W_hh,
              const float* __restrict__ b_ih, const float* __restrict__ b_hh,
              const float* __restrict__ eW1, const float* __restrict__ eb1,
              const float* __restrict__ eW2, const float* __restrict__ eb2,
              const float* __restrict__ eW3, const float* __restrict__ eb3,
              const float* __restrict__ dW1, const float* __restrict__ db1,
              const float* __restrict__ dW2, const float* __restrict__ db2,
              const float* __restrict__ dW3, const float* __restrict__ db3,
              const int* __restrict__ perm, float* __restrict__ out)
{
  __shared__ __align__(16) unsigned short bHiS[2][1536];
  __shared__ __align__(16) unsigned short bLoS[2][1536];
  __shared__ __align__(16) float gS[2304];         // enc z1S / dec d2S
  __shared__ __align__(16) float rnnS[2304];       // rnn chunk; enc z2S / dec d1S
  __shared__ __align__(16) float snapP[NR][HH];
  __shared__ __align__(16) float snapC[NR][HH];
  __shared__ __align__(16) float hS[HH][NR];       // decoder only
  __shared__ __align__(16) float xS[8][NR];
  __shared__ int brS[NR];
  __shared__ int idxS[NR];
  __shared__ float dS[NR];

  const int t  = threadIdx.x;
  const int bb = blockIdx.x;

  for (int i = t; i < 1536; i += NTH) { ((unsigned*)bHiS)[i] = 0; ((unsigned*)bLoS)[i] = 0; }

  if (t < NR) {
    int row = perm ? perm[bb*NR + t] : (bb*NR + t);
    brS[t]  = row;
    idxS[t] = h_lens[row] - 1;   // in [255, 511]
  }
  __syncthreads();

  int maxIdx = idxS[0];
  #pragma unroll
  for (int r = 1; r < NR; ++r) maxIdx = max(maxIdx, idxS[r]);

  const int lane = t & 63;
  const int wv   = t >> 6;                        // 8 waves
  const int col  = lane & 15;
  const int q_a  = lane >> 4;
  const int base = (wv < 2) ? wv*3 : 6 + (wv - 2)*2;   // tiles: w0:0-2 w1:3-5 w2..7: 2 each
  const int nt   = (wv < 2) ? 3 : 2;
  const bool hiHalf = (col >= 8);
  const int colE  = col & 7;
  const int cidxE = idxS[colE];
  const int uA = hiHalf ? 4*(base+1) + q_a : 4*base + q_a;
  const int uB = 4*(base+2) + q_a;               // nt==3 && !hiHalf only
  float cstA = 0.f, cstB = 0.f;

  // ---------------- encoder: 8 -> 256 -> 256 -> 64 ----------------
  if (t < 64) { int r = t >> 3, k = t & 7; xS[k][r] = x[brS[r]*8 + k]; }
  __syncthreads();

  float* z1S = gS;   // [k][8]
  if (t < 256) {
    float acc[NR];
    float b = eb1[t];
    #pragma unroll
    for (int r = 0; r < NR; ++r) acc[r] = b;
    #pragma unroll
    for (int k = 0; k < 8; ++k) { float w = eW1[t*8 + k]; FMA8(acc, w, &xS[k][0]); }
    #pragma unroll
    for (int r = 0; r < NR; ++r) z1S[t*8 + r] = ftanh(acc[r]);
  }
  __syncthreads();
  float* z2S = rnnS; // [k][8]
  if (t < 256) {
    float acc[NR];
    float b = eb2[t];
    #pragma unroll
    for (int r = 0; r < NR; ++r) acc[r] = b;
    const float4* w4 = (const float4*)(eW2 + t*256);
    #pragma unroll 4
    for (int k4 = 0; k4 < 64; ++k4) {
      float4 w = w4[k4];
      FMA8(acc, w.x, z1S + (4*k4+0)*8);
      FMA8(acc, w.y, z1S + (4*k4+1)*8);
      FMA8(acc, w.z, z1S + (4*k4+2)*8);
      FMA8(acc, w.w, z1S + (4*k4+3)*8);
    }
    #pragma unroll
    for (int r = 0; r < NR; ++r) z2S[t*8 + r] = ftanh(acc[r]);
  }
  __syncthreads();
  if (t < 64) {                       // h0 (linear) -> B-frag k = 8+t, buffer 0
    float acc[NR];
    float b = eb3[t];
    #pragma unroll
    for (int r = 0; r < NR; ++r) acc[r] = b;
    const float4* w4 = (const float4*)(eW3 + t*256);
    #pragma unroll 4
    for (int k4 = 0; k4 < 64; ++k4) {
      float4 w = w4[k4];
      FMA8(acc, w.x, z2S + (4*k4+0)*8);
      FMA8(acc, w.y, z2S + (4*k4+1)*8);
      FMA8(acc, w.z, z2S + (4*k4+2)*8);
      FMA8(acc, w.w, z2S + (4*k4+3)*8);
    }
    int u = 8 + t;
    #pragma unroll
    for (int r = 0; r < NR; ++r) {
      unsigned p = packHiLo(acc[r]);
      int id = bidx(u, r);
      bHiS[0][id] = (unsigned short)p;
      bLoS[0][id] = (unsigned short)(p >> 16);
    }
  } else if (t < 128) {               // x part -> k = 0..7, buffer 0
    int tt2 = t - 64; int r = tt2 >> 3, k = tt2 & 7;
    unsigned p = packHiLo(xS[k][r]);
    int id = bidx(k, r);
    bHiS[0][id] = (unsigned short)p;
    bLoS[0][id] = (unsigned short)(p >> 16);
  }

  // ---------------- weights as A-fragments (gate-permuted rows) ----------------
  // n' = 4*unit + gate ; src row = gate*72 + unit. A[m=n'][k], k = kt*32+q_a*8+j.
  short8 Ahi[3][3], Alo[3][3];
  f32x4 biasq[3];
  #pragma unroll
  for (int i = 0; i < 3; ++i) {
    int ii = (i < nt) ? i : 0;
    int u = 4*(base + ii) + q_a;
    biasq[i].x = b_ih[u]       + b_hh[u];
    biasq[i].y = b_ih[72 + u]  + b_hh[72 + u];
    biasq[i].z = b_ih[144 + u] + b_hh[144 + u];
    biasq[i].w = b_ih[216 + u] + b_hh[216 + u];
    int nprime = (base + ii)*16 + col;
    int srcrow = (nprime & 3)*72 + (nprime >> 2);
    #pragma unroll
    for (int kt = 0; kt < 3; ++kt) {
      unsigned h16[8], l16[8];
      #pragma unroll
      for (int j = 0; j < 8; ++j) {
        int k = kt*32 + q_a*8 + j;
        float v = 0.f;
        if (k < 72)      v = W_hh[srcrow*HH + k];
        else if (k < 81) v = W_ih[srcrow*9 + (k - 72)];
        unsigned hi = bf16rne(v);
        h16[j] = hi;
        l16[j] = bf16rne(v - __uint_as_float(hi << 16));
      }
      union { unsigned u4[4]; short8 s; } ch, cl;
      #pragma unroll
      for (int d = 0; d < 4; ++d) {
        ch.u4[d] = h16[2*d] | (h16[2*d+1] << 16);
        cl.u4[d] = l16[2*d] | (l16[2*d+1] << 16);
      }
      Ahi[i][kt] = ch.s;
      Alo[i][kt] = cl.s;
    }
  }

  // ---------------- LSTM over time: one barrier per step ----------------
  int step = 0;
  int par = 0;
  __syncthreads();
  for (int chunk = 0; chunk*32 <= maxIdx; ++chunk) {
    // stage 32 steps of rnn_input -> rnnS[tc][r][k]
    for (int e = t; e < 2304; e += NTH) {
      int r = e / 288, pos = e % 288;
      int tc = pos / 9, kk = pos - tc*9;
      rnnS[tc*72 + r*9 + kk] = rnn[brS[r]*4608 + chunk*288 + pos];
    }
    __syncthreads();
    if (t < 72) {                   // xt for first step of chunk -> buffer par
      int r = t / 9, kk = t - r*9;
      unsigned p = packHiLo(rnnS[t]);
      int id = bidx(72 + kk, r);
      bHiS[par][id] = (unsigned short)p;
      bLoS[par][id] = (unsigned short)(p >> 16);
    }
    __syncthreads();
    int lim = min(31, maxIdx - chunk*32);
    for (int tc = 0; tc <= lim; ++tc, ++step) {
      const int np = par ^ 1;
      short8 bh[3], bl[3];
      #pragma unroll
      for (int kt = 0; kt < 3; ++kt) {
        int rb = (kt*4 + q_a)*128 + col*8;
        bh[kt] = *(const short8*)&bHiS[par][rb];
        bl[kt] = *(const short8*)&bLoS[par][rb];
      }
      f32x4 acc[3];
      #pragma unroll
      for (int i = 0; i < 3; ++i) acc[i] = biasq[i];
      #pragma unroll
      for (int kt = 0; kt < 3; ++kt) {
        #pragma unroll
        for (int i = 0; i < 3; ++i) {
          if (i < nt) {
            acc[i] = __builtin_amdgcn_mfma_f32_16x16x32_bf16(Ahi[i][kt], bh[kt], acc[i], 0, 0, 0);
            acc[i] = __builtin_amdgcn_mfma_f32_16x16x32_bf16(Alo[i][kt], bh[kt], acc[i], 0, 0, 0);
            acc[i] = __builtin_amdgcn_mfma_f32_16x16x32_bf16(Ahi[i][kt], bl[kt], acc[i], 0, 0, 0);
          }
        }
      }
      // move tile base+1's gate quad to the idle high-half lanes
      float sx = swz8(acc[1].x), sy = swz8(acc[1].y), sz = swz8(acc[1].z), sw = swz8(acc[1].w);
      {
        float ig = hiHalf ? sx : acc[0].x;
        float fg = hiHalf ? sy : acc[0].y;
        float gg = hiHalf ? sz : acc[0].z;
        float og = hiHalf ? sw : acc[0].w;
        float hv = cellUpd(ig, fg, gg, og, cstA);
        unsigned p = packHiLo(hv);
        int id = bidx(uA, colE);
        bHiS[np][id] = (unsigned short)p;
        bLoS[np][id] = (unsigned short)(p >> 16);
        if (step == cidxE - 1) snapP[colE][uA] = hv;
        if (step == cidxE)     snapC[colE][uA] = hv;
      }
      if (nt == 3) {
        if (!hiHalf) {
          float hv = cellUpd(acc[2].x, acc[2].y, acc[2].z, acc[2].w, cstB);
          unsigned p = packHiLo(hv);
          int id = bidx(uB, colE);
          bHiS[np][id] = (unsigned short)p;
          bLoS[np][id] = (unsigned short)(p >> 16);
          if (step == cidxE - 1) snapP[colE][uB] = hv;
          if (step == cidxE)     snapC[colE][uB] = hv;
        }
      }
      if (tc < 31 && t < 72) {      // xt for next step -> buffer np
        int r = t / 9, kk = t - r*9;
        unsigned p = packHiLo(rnnS[(tc+1)*72 + t]);
        int id = bidx(72 + kk, r);
        bHiS[np][id] = (unsigned short)p;
        bLoS[np][id] = (unsigned short)(p >> 16);
      }
      __syncthreads();
      par = np;
    }
  }

  // ---------------- decoder: 72 -> 288 -> 288 -> 8 ----------------
  if (t < NR) dS[t] = deltas[brS[t]*TT + idxS[t]];
  __syncthreads();

  // build dec_in into hS[u][r]
  {
    int p = t;              // 0..511
    int u = p % 72, r = p / 72;
    float d = dS[r];
    float sp = snapP[r][u], sc = snapC[r][u];
    hS[u][r] = fmaf(d, sc - sp, sp);
  }
  if (t < 64) {
    int p = 512 + t;        // 512..575 -> r=7, u=8+t
    int u = p % 72, r = p / 72;
    float d = dS[r];
    float sp = snapP[r][u], sc = snapC[r][u];
    hS[u][r] = fmaf(d, sc - sp, sp);
  }
  __syncthreads();

  // layer1: 288 x 72 — thread t < 288 owns output column t
  float* d1S = rnnS; // [k][8]
  if (t < 288) {
    float acc[NR];
    float b = db1[t];
    #pragma unroll
    for (int r = 0; r < NR; ++r) acc[r] = b;
    const float4* w4 = (const float4*)(dW1 + t*HH);
    #pragma unroll 2
    for (int k4 = 0; k4 < 18; ++k4) {
      float4 w = w4[k4];
      FMA8(acc, w.x, &hS[4*k4+0][0]);
      FMA8(acc, w.y, &hS[4*k4+1][0]);
      FMA8(acc, w.z, &hS[4*k4+2][0]);
      FMA8(acc, w.w, &hS[4*k4+3][0]);
    }
    #pragma unroll
    for (int r = 0; r < NR; ++r) d1S[t*8 + r] = ftanh(acc[r]);
  }
  __syncthreads();

  // layer2: 288 x 288
  float* d2S = gS;   // [k][8]
  if (t < 288) {
    float acc[NR];
    float b = db2[t];
    #pragma unroll
    for (int r = 0; r < NR; ++r) acc[r] = b;
    const float4* w4 = (const float4*)(dW2 + t*288);
    #pragma unroll 4
    for (int k4 = 0; k4 < 72; ++k4) {
      float4 w = w4[k4];
      FMA8(acc, w.x, d1S + (4*k4+0)*8);
      FMA8(acc, w.y, d1S + (4*k4+1)*8);
      FMA8(acc, w.z, d1S + (4*k4+2)*8);
      FMA8(acc, w.w, d1S + (4*k4+3)*8);
    }
    #pragma unroll
    for (int r = 0; r < NR; ++r) d2S[t*8 + r] = ftanh(acc[r]);
  }
  __syncthreads();

  // layer3: 8 x 288 (linear) + scatter store
  if (t < 64) {
    int o = t & 7, r = t >> 3;
    float acc3 = db3[o];
    const float* wr = dW3 + o*288;
    #pragma unroll 4
    for (int k = 0; k < 288; ++k) acc3 = fmaf(wr[k], d2S[k*8 + r], acc3);
    out[brS[r]*8 + o] = acc3;
  }
}

extern "C" void kernel_launch(void* const* d_in, const int* in_sizes, int n_in,
                              void* d_out, int out_size, void* d_ws, size_t ws_size,
                              hipStream_t stream) {
  const float* x      = (const float*)d_in[0];
  const float* rnn    = (const float*)d_in[1];
  const float* deltas = (const float*)d_in[2];
  const int*   h_lens = (const int*)  d_in[3];
  const float* W_ih   = (const float*)d_in[4];
  const float* W_hh   = (const float*)d_in[5];
  const float* b_ih   = (const float*)d_in[6];
  const float* b_hh   = (const float*)d_in[7];
  const float* eW1    = (const float*)d_in[8];
  const float* eb1    = (const float*)d_in[9];
  const float* eW2    = (const float*)d_in[10];
  const float* eb2    = (const float*)d_in[11];
  const float* eW3    = (const float*)d_in[12];
  const float* eb3    = (const float*)d_in[13];
  const float* dW1    = (const float*)d_in[14];
  const float* db1    = (const float*)d_in[15];
  const float* dW2    = (const float*)d_in[16];
  const float* db2    = (const float*)d_in[17];
  const float* dW3    = (const float*)d_in[18];
  const float* db3    = (const float*)d_in[19];
  float* out = (float*)d_out;

  int* perm = nullptr;
  if (ws_size >= 2048 * sizeof(int)) {
    perm = (int*)d_ws;
    cfm_sort<<<1, 256, 0, stream>>>(h_lens, perm);
  }
  cfm_main<<<2048/NR, NTH, 0, stream>>>(x, rnn, deltas, h_lens, W_ih, W_hh, b_ih, b_hh,
                                        eW1, eb1, eW2, eb2, eW3, eb3,
                                        dW1, db1, dW2, db2, dW3, db3,
                                        perm, out);
}